// Round 6
// baseline (516.200 us; speedup 1.0000x reference)
//
#include <hip/hip_runtime.h>

// LocallyConnected1d via bf16 MFMA + split-K:
//   out[b,o,l] = sum_{i,k} x[b,i,l+k-4]*w[i,o,k,l] + bias[o,l]
//
// R6 theory: R1-R5 all fit "beyond-L1 requested bytes / ~4.6 TB/s" (R4 vs R5:
// same time at 1.7x different *line* traffic -> byte-side limit). So: cut bytes.
// Block = 32 l x 16 o x ALL 64 b x 16-of-64 i (split-K over input channels).
// Grid 16 lt x 4 os x 4 ks = 256 = 1 block/CU, 1024 thr = 16 waves = 4/SIMD.
//  * weights: read EXACTLY ONCE device-wide (75.5 MB, was 302), full 128B lines.
//  * x: 42 MB (os x4 + 1.25 halo), staged once to LDS as bf16.
//  * partials: fp32 unsafeAtomicAdd into out (4 adds/element, low contention),
//    after a bias-init kernel.
// K-order k-major (kk = k*16 + i_local) => A-operand is RAW x from the LDS
// window Xs[lw][b][i16]; B = weights transposed through LDS per step.
// 5 MFMA steps of K=32 (144 real + 16 zero-pad); 2 barriers/step (10 vs R5's 36).

#define CIN   64
#define COUT  64
#define SEQ   512
#define KS    9
#define LT    32
#define OT    16
#define ISP   16                       // i-channels per block (split-K = 4)
#define XLS   1032                     // Xs lw-stride (ush): 64b*16i=1024 + 8 pad
                                       //  (16B-mult for b128; word%32=4 spreads staging banks)
#define BOS   40                       // Bs o-stride (ush): 32 kk + 8 pad (16B-mult, odd 16B count)
#define BLS   (OT*BOS + 8)             // Bs lrel-stride = 648 ush (16B-mult, odd 16B count)
#define XS_ELEMS (41*XLS)              // rows lw=0..40 (40 = zero row for k=9 pad reads)
#define BS_ELEMS (LT*BLS)
#define LDS_BYTES ((XS_ELEMS + BS_ELEMS)*2)   // 126096 B -> 1 block/CU
#define WSTR  (COUT*KS*SEQ)            // weight i-stride (floats)

typedef __attribute__((ext_vector_type(8))) short bf16x8;
typedef __attribute__((ext_vector_type(4))) float f32x4;

__device__ __forceinline__ ushort f2bf(float f) {
    return (ushort)((__float_as_uint(f) + 0x8000u) >> 16);
}
__device__ __forceinline__ uint pack2bf(float a0, float a1) {
    uint u0 = __float_as_uint(a0) + 0x8000u;
    uint u1 = __float_as_uint(a1) + 0x8000u;
    return __builtin_amdgcn_perm(u1, u0, 0x07060302);  // (bf(a1)<<16)|bf(a0)
}

// out[b,o,l] = bias[o,l]; flat float4 idx: (b*64+o)*512+l mod 32768 = o*512+l.
__global__ __launch_bounds__(256)
void init_out(const float* __restrict__ bias, float* __restrict__ out)
{
    int idx = blockIdx.x * 256 + threadIdx.x;        // float4 index, 524288 total
    ((float4*)out)[idx] = ((const float4*)bias)[idx & 8191];
}

__global__ __launch_bounds__(1024, 4)
void lc1d_mfma(const float* __restrict__ x, const float* __restrict__ w,
               float* __restrict__ out)
{
    extern __shared__ ushort lds[];
    ushort* Xs = lds;              // [lw 0..40][b 0..63][il 0..15]
    ushort* Bs = lds + XS_ELEMS;   // [lrel 0..31][o 0..15][kk 0..31]

    const int tid  = threadIdx.x;
    const int lane = tid & 63;
    const int wv   = tid >> 6;          // 0..15
    const int lt = blockIdx.x;          // 0..15
    const int os = blockIdx.y;          // 0..3
    const int ks = blockIdx.z;          // 0..3
    const int l0 = lt * LT;
    const int o0 = os * OT;
    const int I0 = ks * ISP;

    // ---- weight-staging lane map: l fastest -> full-128B-line streaming ----
    const int lq  = tid & 7;            // l-quad 0..7
    const int oo  = (tid >> 3) & 15;    // o
    const int k2  = (tid >> 7) & 1;     // k within step (wave-uniform)
    const int ii4 = tid >> 8;           // i-group 0..3 (4 i's per thread)

    const float* wbase = w + ((size_t)(I0 + ii4*4) * COUT + (o0 + oo)) * (KS*SEQ)
                           + l0 + lq*4;
    float4 pf[4];

    // step c: k = 2c + k2 (c=4,k2=1 -> k=9: zero-pad)
    #define LOAD_STEP(c) {                                                       \
        const int k_ = 2*(c) + k2;                                               \
        if (k_ < KS) {                                                           \
            const float* p_ = wbase + (size_t)k_ * SEQ;                          \
            _Pragma("unroll")                                                    \
            for (int di = 0; di < 4; ++di)                                       \
                pf[di] = *(const float4*)(p_ + (size_t)di * WSTR);               \
        } else {                                                                 \
            _Pragma("unroll")                                                    \
            for (int di = 0; di < 4; ++di)                                       \
                pf[di] = make_float4(0.f, 0.f, 0.f, 0.f);                        \
        }                                                                        \
    }

    LOAD_STEP(0)   // oldest in vmcnt queue; lands under Xs staging

    // ---- stage Xs once: Xs[lw][b][il] = bf16(x[b, I0+il, l0-4+lw]) ----
    // Phase 1 (lw 0..31, coalesced): lanes = 8 l-quads x 8 rows -> 8 x 128B.
    {
        const int sub  = tid & 7;           // l-quad (lw = sub*4..+3)
        const int rowb = tid >> 3;          // 0..127
        const int b  = rowb & 63;
        #pragma unroll
        for (int p = 0; p < 8; ++p) {
            const int il = (rowb >> 6) + 2*p;
            const float* src = x + ((size_t)(b*CIN + I0 + il))*SEQ + (l0 - 4) + sub*4;
            float4 v = make_float4(0.f, 0.f, 0.f, 0.f);
            if (!(lt == 0 && sub == 0)) v = *(const float4*)src;
            ushort* dst = Xs + (sub*4)*XLS + b*ISP + il;
            dst[0*XLS] = f2bf(v.x);
            dst[1*XLS] = f2bf(v.y);
            dst[2*XLS] = f2bf(v.z);
            dst[3*XLS] = f2bf(v.w);
        }
        // Phase 2 (lw 32..39): 1 row/thread, 2 quads (scattered; ~20% of x bytes).
        const int b2  = tid & 63;
        const int il2 = tid >> 6;
        const float* src2 = x + ((size_t)(b2*CIN + I0 + il2))*SEQ + (l0 - 4);
        #pragma unroll
        for (int q = 8; q < 10; ++q) {
            float4 v = make_float4(0.f, 0.f, 0.f, 0.f);
            if (!(lt == 15 && q == 9)) v = *(const float4*)(src2 + q*4);
            ushort* dst = Xs + (q*4)*XLS + b2*ISP + il2;
            dst[0*XLS] = f2bf(v.x);
            dst[1*XLS] = f2bf(v.y);
            dst[2*XLS] = f2bf(v.z);
            dst[3*XLS] = f2bf(v.w);
        }
        Xs[40*XLS + tid] = 0;   // lw=40 zero row: read when k=9 (pad), keeps NaN out
    }

    f32x4 acc[4][2];
    #pragma unroll
    for (int a = 0; a < 4; ++a) { acc[a][0] = (f32x4)0.0f; acc[a][1] = (f32x4)0.0f; }

    // MFMA lane offsets. A: m=b_local=lane&15, kgrp=lane>>4:
    //   kk = kgrp*8+j -> k_off = kgrp>>1, il = (kgrp&1)*8 + j.
    const int am   = (lane & 15) * ISP + ((lane >> 4) & 1) * 8;
    const int akof = lane >> 5;                  // k offset 0/1
    const int boff = (lane & 15) * BOS + (lane >> 4) * 8;
    const int lrg  = (wv & 7) * 4;               // wave's lrel base
    const int btp  = (wv >> 3) * 2;              // wave's b-tile base

    __syncthreads();   // Xs ready

    for (int c = 0; c < 5; ++c) {
        // ---- transpose pf -> Bs[lrel=lq*4+dl][oo][kk = k2*16 + ii4*4 + di] ----
        #pragma unroll
        for (int s = 0; s < 2; ++s) {
            #pragma unroll
            for (int dl = 0; dl < 4; ++dl) {
                uint pk = pack2bf((&pf[2*s].x)[dl], (&pf[2*s+1].x)[dl]);
                *(uint*)(Bs + (lq*4+dl)*BLS + oo*BOS + k2*16 + ii4*4 + 2*s) = pk;
            }
        }
        __syncthreads();              // Bs(c) ready
        if (c < 4) LOAD_STEP(c + 1)   // next step's weights fly during MFMA

        #pragma unroll
        for (int dlr = 0; dlr < 4; ++dlr) {
            const int lrel = lrg + dlr;
            bf16x8 Bf = *(const bf16x8*)(Bs + lrel*BLS + boff);
            #pragma unroll
            for (int dbt = 0; dbt < 2; ++dbt) {
                const ushort* Ap = Xs + (lrel + 2*c + akof)*XLS + (btp + dbt)*(16*ISP) + am;
                bf16x8 Af = *(const bf16x8*)Ap;
                acc[dlr][dbt] = __builtin_amdgcn_mfma_f32_16x16x32_bf16(
                                    Af, Bf, acc[dlr][dbt], 0, 0, 0);
            }
        }
        __syncthreads();              // all reads done before Bs overwrite
    }

    // ---- epilogue: atomic accumulate partials (C: col=o=lane&15, row=b) ----
    const int orow = o0 + (lane & 15);
    const int rgrp = (lane >> 4) * 4;
    #pragma unroll
    for (int dlr = 0; dlr < 4; ++dlr) {
        const int l = l0 + lrg + dlr;
        #pragma unroll
        for (int dbt = 0; dbt < 2; ++dbt) {
            const int bb = (btp + dbt) * 16 + rgrp;
            #pragma unroll
            for (int r = 0; r < 4; ++r) {
                unsafeAtomicAdd(out + ((size_t)((bb + r)*COUT + orow))*SEQ + l,
                                acc[dlr][dbt][r]);
            }
        }
    }
}

extern "C" void kernel_launch(void* const* d_in, const int* in_sizes, int n_in,
                              void* d_out, int out_size, void* d_ws, size_t ws_size,
                              hipStream_t stream) {
    const float* x    = (const float*)d_in[0];
    const float* wgt  = (const float*)d_in[1];
    const float* bias = (const float*)d_in[2];
    float* out        = (float*)d_out;

    init_out<<<dim3(2048), dim3(256), 0, stream>>>(bias, out);

    hipFuncSetAttribute((const void*)lc1d_mfma,
                        hipFuncAttributeMaxDynamicSharedMemorySize, LDS_BYTES);
    dim3 grid(16, 4, 4);   // (l-tile, o-split, k-split); os/ks siblings same XCD
    lc1d_mfma<<<grid, 1024, LDS_BYTES, stream>>>(x, wgt, out);
}

// Round 7
// 152.493 us; speedup vs baseline: 3.3851x; 3.3851x over previous
//
#include <hip/hip_runtime.h>

// LocallyConnected1d via bf16 MFMA: out[b,o,l] = sum_{i,k} x[b,i,l+k-4]*w[i,o,k,l] + bias[o,l]
// 512 per-l GEMMs (M=b=64, N=o=16, K=576 k-major => A-operand is RAW x window).
//
// R7: weights-once WITHOUT atomics (R6's fp32 global atomics wrote 262 MB to HBM
// and serialized: 427 us). Partition (l,o): block = 8 l x 16 o x ALL 64 b, full
// K=576. Grid 64 lt x 4 os = 256 = 1 block/CU.
//  * weights: read exactly once device-wide (75.5 MB, was 302 in R5).
//  * x: 67 MB (halo x2 at LT=8, os x4) — small next to w.
//  * out: written once, bias folded -> WRITE 8.2 MB, single kernel.
// R1-R5 fit: per-CU request-byte pipe ~7.5 B/cyc (4.6 TB/s device). Budget
// 151 MB -> ~33 us.
// 18 K-steps (9 k-taps x 2 i-halves), distance-2 weight prefetch (pfA/pfB),
// 512 stager threads (i-pair float4 -> pack2bf b32 into Bs), R6's validated
// Bs geometry (BOS=40, BLS=648), Xs stride 72 (2-way max on b128 reads).

#define CIN   64
#define COUT  64
#define SEQ   512
#define KS    9
#define LT    8
#define OT    16
#define LWIN  16                      // LT + 8 halo
#define XSTR  72                      // Xs b-stride (ush): 64 i + 8 pad
#define XLW   (64*XSTR)               // Xs lw-stride = 4608 ush (64 b rows)
#define BOS   40                      // Bs o-stride (ush): 32 kk + 8 pad
#define BLS   (OT*BOS + 8)            // Bs lrel-stride = 648 ush
#define NSTEP 18
#define WSTR  (COUT*KS*SEQ)           // weight i-stride (floats)
#define XS_ELEMS (LWIN*XLW)           // 73728 ush = 144 KB
#define BS_ELEMS (LT*BLS)             // 5184 ush  = 10.1 KB
#define LDS_BYTES ((XS_ELEMS + BS_ELEMS)*2)   // 157824 B -> 1 block/CU

typedef __attribute__((ext_vector_type(8))) short bf16x8;
typedef __attribute__((ext_vector_type(4))) float f32x4;

__device__ __forceinline__ ushort f2bf(float f) {
    return (ushort)((__float_as_uint(f) + 0x8000u) >> 16);
}
__device__ __forceinline__ uint pack2bf(float a0, float a1) {
    uint u0 = __float_as_uint(a0) + 0x8000u;
    uint u1 = __float_as_uint(a1) + 0x8000u;
    return __builtin_amdgcn_perm(u1, u0, 0x07060302);  // (bf(a1)<<16)|bf(a0)
}

__global__ __launch_bounds__(1024, 4)
void lc1d_mfma(const float* __restrict__ x, const float* __restrict__ w,
               const float* __restrict__ bias, float* __restrict__ out)
{
    extern __shared__ ushort lds[];
    ushort* Xs = lds;              // [lw 0..15][b 0..63][i 0..63] stride XSTR
    ushort* Bs = lds + XS_ELEMS;   // [lrel 0..7][o 0..15][kk 0..31]

    const int tid  = threadIdx.x;
    const int lane = tid & 63;
    const int wv   = tid >> 6;          // 0..15
    const int lt = blockIdx.x >> 2;     // 0..63
    const int os = blockIdx.x & 3;      // 0..3
    const int l0 = lt * LT;
    const int o0 = os * OT;

    // ---- weight staging (tid < 512): thread = (lh, oo, ip) ----
    const int lh = tid & 1;             // which 16B half of the 32B l-span
    const int oo = (tid >> 1) & 15;     // o
    const int ip = (tid >> 5) & 15;     // i-pair 0..15 (i = ih*32 + 2ip + {0,1})
    const bool stager = (tid < 512);

    const float* wbase = w + ((size_t)(2*ip) * COUT + (o0 + oo)) * (KS*SEQ)
                           + l0 + lh*4;
    float4 pfA[2], pfB[2];

    // step c: k = c>>1 (tap), ih = c&1 (i-half). 18 steps cover K=576 exactly.
    #define LOAD_STEP(pf, c) if (stager) {                                       \
        const int k_ = (c) >> 1, ih_ = (c) & 1;                                  \
        const float* p_ = wbase + (size_t)(ih_*32) * WSTR + (size_t)k_ * SEQ;    \
        pf[0] = *(const float4*)p_;                                              \
        pf[1] = *(const float4*)(p_ + WSTR);                                     \
    }

    // transpose+convert: kk = 2ip+{0,1} packed -> b32 at Bs[lrel=lh*4+dl][oo][2ip]
    #define WRITE_BS(pf) if (stager) {                                           \
        _Pragma("unroll")                                                        \
        for (int dl = 0; dl < 4; ++dl) {                                         \
            uint pk = pack2bf((&pf[0].x)[dl], (&pf[1].x)[dl]);                   \
            *(uint*)(Bs + (lh*4+dl)*BLS + oo*BOS + 2*ip) = pk;                   \
        }                                                                        \
    }

    LOAD_STEP(pfA, 0)
    LOAD_STEP(pfB, 1)

    // ---- stage Xs once: Xs[lw][b][i] = bf16(x[b, i, l0-4+lw]) ----
    // 4096 rows (64b x 64i) x 4 quads = 16384 float4; flat = tid + 1024*it.
    #pragma unroll
    for (int it = 0; it < 16; ++it) {
        int flat = tid + 1024*it;
        int row = flat >> 2;           // b*64 + i
        int q   = flat & 3;            // lw quad 0..3 (lw = q*4..+3)
        int b = row >> 6, i = row & 63;
        const float* src = x + ((size_t)(b*CIN + i))*SEQ + (l0 - 4) + q*4;
        float4 v = make_float4(0.f, 0.f, 0.f, 0.f);
        if (!((lt == 0 && q == 0) || (lt == 63 && q == 3)))
            v = *(const float4*)src;
        ushort* dst = Xs + (q*4)*XLW + b*XSTR + i;
        dst[0*XLW] = f2bf(v.x);
        dst[1*XLW] = f2bf(v.y);
        dst[2*XLW] = f2bf(v.z);
        dst[3*XLW] = f2bf(v.w);
    }

    f32x4 acc[2];
    acc[0] = (f32x4)0.0f;
    acc[1] = (f32x4)0.0f;

    // wave tiles: lrel = wv&7, b-tiles btb, btb+1 where btb = (wv>>3)*2.
    const int lrel = wv & 7;
    const int btb  = (wv >> 3) * 2;
    const int am   = (lane & 15) * XSTR + (lane >> 4) * 8;   // b-lane + kgrp (ih added per step)
    const int boff = lrel*BLS + (lane & 15) * BOS + (lane >> 4) * 8;

    __syncthreads();   // Xs ready

    #define DO_MFMA(c) {                                                         \
        const int k_ = (c) >> 1, ih_ = (c) & 1;                                  \
        bf16x8 Bf = *(const bf16x8*)(Bs + boff);                                 \
        const ushort* Arow = Xs + (lrel + k_)*XLW + ih_*32 + am;                 \
        _Pragma("unroll")                                                        \
        for (int jt = 0; jt < 2; ++jt) {                                         \
            bf16x8 Af = *(const bf16x8*)(Arow + (btb + jt)*(16*XSTR));           \
            acc[jt] = __builtin_amdgcn_mfma_f32_16x16x32_bf16(Af, Bf, acc[jt],   \
                                                              0, 0, 0);          \
        }                                                                        \
    }

    for (int cc = 0; cc < NSTEP; cc += 2) {
        WRITE_BS(pfA)
        __syncthreads();                        // Bs(cc) ready
        if (cc + 2 < NSTEP) LOAD_STEP(pfA, cc + 2)
        DO_MFMA(cc)
        __syncthreads();                        // reads done before overwrite

        WRITE_BS(pfB)
        __syncthreads();                        // Bs(cc+1) ready
        if (cc + 3 < NSTEP) LOAD_STEP(pfB, cc + 3)
        DO_MFMA(cc + 1)
        __syncthreads();
    }

    // ---- epilogue: C col = o = lane&15, row = b_local = (lane>>4)*4 + r ----
    const int l    = l0 + lrel;
    const int orow = o0 + (lane & 15);
    const int rbase = (lane >> 4) * 4;
    const float bv = bias[orow*SEQ + l];
    #pragma unroll
    for (int jt = 0; jt < 2; ++jt) {
        #pragma unroll
        for (int r = 0; r < 4; ++r) {
            const int b = (btb + jt)*16 + rbase + r;
            out[((size_t)(b*COUT + orow))*SEQ + l] = acc[jt][r] + bv;
        }
    }
}

extern "C" void kernel_launch(void* const* d_in, const int* in_sizes, int n_in,
                              void* d_out, int out_size, void* d_ws, size_t ws_size,
                              hipStream_t stream) {
    const float* x    = (const float*)d_in[0];
    const float* wgt  = (const float*)d_in[1];
    const float* bias = (const float*)d_in[2];
    float* out        = (float*)d_out;

    hipFuncSetAttribute((const void*)lc1d_mfma,
                        hipFuncAttributeMaxDynamicSharedMemorySize, LDS_BYTES);
    dim3 grid(256);   // blockIdx.x = lt*4 + os; every (o,l,b) owned by one block
    lc1d_mfma<<<grid, 1024, LDS_BYTES, stream>>>(x, wgt, bias, out);
}

// Round 8
// 134.061 us; speedup vs baseline: 3.8505x; 1.1375x over previous
//
#include <hip/hip_runtime.h>

// LocallyConnected1d via bf16 MFMA: out[b,o,l] = sum_{i,k} x[b,i,l+k-4]*w[i,o,k,l] + bias[o,l]
// 512 per-l GEMMs (M=b=64, N=o (8 real, 8 zero-padded), K=576 k-major).
//
// R8: fix HBM efficiency (R7: 1.8 TB/s = 32-B sector reads + cross-XCD line split).
//  * LT=16, OT=8: weight instrs request full 64-B segments; line-mate blocks
//    (lt pairs, blockIdx +-8) share an XCD -> L2 merges -> HBM sees full lines once.
//  * grid x = lt*8 + os: all blocks of an os-slice on one XCD (w slice streams
//    its L2 once); x os-siblings served by memory-side L3.
//  * i-half passes: Xs[24 lw][64 b][32 i] bf16 = 120 KB, x staged twice.
//  * Bs double-buffered (2 slots) + 3-slot register ring -> 1 barrier/step,
//    18 steps fully unrolled. Stagers = waves 0..7; waves 8..15 never touch vmem.
//  * B lanes n>=8 read a shared 32-ush zero region (broadcast = free).

#define CIN   64
#define COUT  64
#define SEQ   512
#define KS    9
#define LT    16
#define OT    8
#define LWIN  24
#define WSTR  (COUT*KS*SEQ)            // weight i-stride (floats)
#define XBS   40                       // Xs b-stride (ush): 32 i + 8 pad (5 granules, coprime 8)
#define XLW   (64*XBS)                 // Xs lw-stride = 2560 ush
#define XS_ELEMS (LWIN*XLW)            // 61440 ush = 120 KB
#define BOS   40                       // Bs o-stride (ush)
#define BLS   (OT*BOS + 8)             // Bs l-stride = 328 ush (41 granules, odd)
#define BSLOT (LT*BLS)                 // 5248 ush per buffer
#define ZOFF  (XS_ELEMS + 2*BSLOT)     // zero region for n>=8 B-frag reads
#define LDS_USH (ZOFF + 64)            // 72000 ush
#define LDS_BYTES (LDS_USH*2)          // 144000 B -> 1 block/CU
#define NSTEP 18                       // 2 i-halves x 9 k-taps

typedef __attribute__((ext_vector_type(8))) short bf16x8;
typedef __attribute__((ext_vector_type(4))) float f32x4;

__device__ __forceinline__ uint pack2bf(float a0, float a1) {
    uint u0 = __float_as_uint(a0) + 0x8000u;
    uint u1 = __float_as_uint(a1) + 0x8000u;
    return __builtin_amdgcn_perm(u1, u0, 0x07060302);  // (bf(a1)<<16)|bf(a0)
}

__global__ __launch_bounds__(1024, 4)
void lc1d_mfma(const float* __restrict__ x, const float* __restrict__ w,
               const float* __restrict__ bias, float* __restrict__ out)
{
    extern __shared__ ushort lds[];
    ushort* Xs = lds;                    // [lw 0..23][b 0..63][ii 0..31]
    ushort* BsB = lds + XS_ELEMS;        // 2 x [l 0..15][o 0..7][kk 0..31]

    const int tid  = threadIdx.x;
    const int lane = tid & 63;
    const int wvid = tid >> 6;           // 0..15
    const int bt = wvid & 3;             // wave's b-tile (16 b)
    const int lg = wvid >> 2;            // wave's l-group (4 l)
    const int lt = blockIdx.x >> 3;      // 0..31
    const int os = blockIdx.x & 7;       // 0..7 == XCD id
    const int l0 = lt * LT;
    const int o0 = os * OT;

    // ---- weight stager mapping (tid < 512): 64-B-contiguous l spans ----
    const bool stager = (tid < 512);
    const int lf  = tid & 3;             // float4 within the 16-l span
    const int oo  = (tid >> 2) & 7;      // o
    const int ipp = (tid >> 5) & 15;     // i-pair within 32-i half

    const float* wbase = w + ((size_t)(2*ipp)*COUT + (o0 + oo))*(KS*SEQ) + l0 + lf*4;

    float4 rA[3], rB[3];                 // 3-slot ring, i-pair per slot

    // step s: ih = s/9 (i-half), k = s%9 (tap)
    #define LOAD_RING(sl, s) if (stager && (s) < NSTEP) {                        \
        const int ih_ = (s) / 9, k_ = (s) - 9*ih_;                               \
        const float* p_ = wbase + (size_t)ih_*32*WSTR + k_*SEQ;                  \
        rA[sl] = *(const float4*)p_;                                             \
        rB[sl] = *(const float4*)(p_ + WSTR);                                    \
    }

    // transpose+cvt ring slot -> Bs parity (s&1): b32 of i-pair at [l][o][kk]
    #define WRITE_BS(sl, s) if (stager) {                                        \
        ushort* dst_ = BsB + ((s)&1)*BSLOT + oo*BOS + 2*ipp;                     \
        _Pragma("unroll")                                                        \
        for (int dl = 0; dl < 4; ++dl) {                                         \
            uint pk_ = pack2bf((&rA[sl].x)[dl], (&rB[sl].x)[dl]);                \
            *(uint*)(dst_ + (lf*4+dl)*BLS) = pk_;                                \
        }                                                                        \
    }

    // stage Xs for i-half ih: Xs[lw][b][ii] = bf16(x[b, ih*32+ii, l0-4+lw])
    // thread = (qq = l-quad 0..5 of 8, rp = (b, ii-pair)); pack ii-pairs -> b32.
    #define STAGE_XS(ih) {                                                       \
        const int qq  = tid & 7;                                                 \
        const int rp0 = tid >> 3;                                                \
        if (qq < 6) {                                                            \
            _Pragma("unroll")                                                    \
            for (int it = 0; it < 8; ++it) {                                     \
                const int rp = rp0 + it*128;                                     \
                const int b_ = rp >> 4, ip_ = rp & 15;                           \
                const float* s0 = x + ((size_t)(b_*CIN) + (ih)*32 + 2*ip_)*SEQ   \
                                    + (l0 - 4) + qq*4;                           \
                float4 v0 = make_float4(0.f,0.f,0.f,0.f), v1 = v0;               \
                if (!((lt == 0 && qq == 0) || (lt == 31 && qq == 5))) {          \
                    v0 = *(const float4*)s0;                                     \
                    v1 = *(const float4*)(s0 + SEQ);                             \
                }                                                                \
                ushort* d_ = Xs + b_*XBS + 2*ip_;                                \
                _Pragma("unroll")                                                \
                for (int dl = 0; dl < 4; ++dl)                                   \
                    *(uint*)(d_ + (qq*4+dl)*XLW) = pack2bf((&v0.x)[dl],          \
                                                           (&v1.x)[dl]);         \
            }                                                                    \
        }                                                                        \
    }

    // MFMA lane constants
    const int aoff = (bt*16 + (lane & 15))*XBS + (lane >> 4)*8;
    const int boff = (lane & 15)*BOS + (lane >> 4)*8;
    const bool nhi = (lane & 15) >= 8;                 // dead o lanes -> zeros
    const ushort* zptr = lds + ZOFF + (lane >> 4)*8;   // shared (broadcast) zeros

    f32x4 acc[4];
    #pragma unroll
    for (int j = 0; j < 4; ++j) acc[j] = (f32x4)0.0f;

    #define DO_MFMA(s) {                                                         \
        const int k_ = (s) % 9;                                                  \
        const ushort* BsS = BsB + ((s)&1)*BSLOT;                                 \
        _Pragma("unroll")                                                        \
        for (int dl = 0; dl < 4; ++dl) {                                         \
            const int ll = lg*4 + dl;                                            \
            bf16x8 Af = *(const bf16x8*)(Xs + (ll + k_)*XLW + aoff);             \
            const ushort* Bp = nhi ? zptr : (BsS + ll*BLS + boff);               \
            bf16x8 Bf = *(const bf16x8*)Bp;                                      \
            acc[dl] = __builtin_amdgcn_mfma_f32_16x16x32_bf16(Af, Bf, acc[dl],   \
                                                              0, 0, 0);          \
        }                                                                        \
    }

    // one barrier per step: during step s, stagers fill Bs parity (s+1)&1
    #define STEP(s) {                                                            \
        if ((s) < NSTEP-1) WRITE_BS(((s)+1)%3, (s)+1)                            \
        LOAD_RING(((s)+1)%3, (s)+4)                                              \
        DO_MFMA(s)                                                               \
        __syncthreads();                                                         \
    }

    // ---- prologue ----
    LOAD_RING(0, 0)
    LOAD_RING(1, 1)
    LOAD_RING(2, 2)
    if (tid < 64) lds[ZOFF + tid] = 0;
    STAGE_XS(0)
    WRITE_BS(0, 0)
    LOAD_RING(0, 3)
    __syncthreads();   // Xs(ih0) + Bs(step0) + zero region ready

    STEP(0)  STEP(1)  STEP(2)  STEP(3)  STEP(4)
    STEP(5)  STEP(6)  STEP(7)  STEP(8)

    STAGE_XS(1)        // all step-8 Xs reads completed at STEP(8)'s barrier
    __syncthreads();

    STEP(9)  STEP(10) STEP(11) STEP(12) STEP(13)
    STEP(14) STEP(15) STEP(16) STEP(17)

    // ---- epilogue: C col = o' = lane&15 (store only o'<8), row = b_local ----
    if (!nhi) {
        const int og = o0 + (lane & 15);
        const int rb = (lane >> 4)*4;
        #pragma unroll
        for (int dl = 0; dl < 4; ++dl) {
            const int lgl = l0 + lg*4 + dl;
            const float bv = bias[og*SEQ + lgl];
            #pragma unroll
            for (int r = 0; r < 4; ++r) {
                const int bg = bt*16 + rb + r;
                out[((size_t)(bg*COUT + og))*SEQ + lgl] = acc[dl][r] + bv;
            }
        }
    }
}

extern "C" void kernel_launch(void* const* d_in, const int* in_sizes, int n_in,
                              void* d_out, int out_size, void* d_ws, size_t ws_size,
                              hipStream_t stream) {
    const float* x    = (const float*)d_in[0];
    const float* wgt  = (const float*)d_in[1];
    const float* bias = (const float*)d_in[2];
    float* out        = (float*)d_out;

    hipFuncSetAttribute((const void*)lc1d_mfma,
                        hipFuncAttributeMaxDynamicSharedMemorySize, LDS_BYTES);
    dim3 grid(256);   // blockIdx = lt*8 + os: os == XCD id; lt line-mates co-XCD
    lc1d_mfma<<<grid, 1024, LDS_BYTES, stream>>>(x, wgt, bias, out);
}